// Round 10
// baseline (306.745 us; speedup 1.0000x reference)
//
#include <hip/hip_runtime.h>

// SSIM 3D, round 13. Separable rank-1 window (u ⊗ v ⊗ t), fused W->H->D.
// r12 post-mortem: DSUB=8 @(256,2) compiled clean (WRITE 65KB) but VGPR=72
// > 64 -> 4 waves/SIMD cap (m69: waves halve past 64) -> still 16 waves/CU;
// +20% halo work with zero TLP gain. Full occupancy gate: VGPR<=64 AND no
// spill at the pin AND small LDS AND grid >= capacity AND proven codegen.
// This round satisfies all five simultaneously:
//  - 128-thread blocks (2 waves). Each wave keeps r8's EXACT per-wave body
//    (8 rows x 32-col stripe, float4 W loads, float2 ring H/D) -> register
//    demand is r8's proven 64-fit. __launch_bounds__(128,4) -> pin 64
//    (session formula 512/min_waves/2, per-EU semantics).
//  - Block tile 4 rows x 64 cols x DSUB=8 -> 4096 blocks; LDS 10.25 KB ->
//    15 blocks/CU = 30 waves/CU (WG cap 16 doesn't bind; grid 16/CU feeds it).
//  - 12 slices as PROLOGUE(2 phases, i=0,1: D-conv statically dead -> minimal
//    junction pressure) + proven 5-phase loop x2 (ring literals {2,3,4,0,1}).
//  - Barrier-free wave-private LDS exchange + asm fences (r8, verified);
//    plain partials tail; separate finalize kernel.
// Tripwires: VGPR_Count == 64 (72+ => bounds formula wrong -> revert);
// WRITE_SIZE < 1 MB (spill => revert to r8 as final; VGPR_Count lies);
// occupancy up but dur flat => chain not TLP-coverable => r8 is the ceiling.

#define NDIM 128
#define TH 4
#define WR (TH + 4)            // 8 W-conv rows
#define DSUB 8
#define SW 64                  // block col-stripe width (2 waves x 32)
#define NSS (NDIM / SW)        // 2
#define NHT (NDIM / TH)        // 32
#define NDT (NDIM / DSUB)      // 16
#define NB 4
#define NBLK (NHT * NDT * NB * NSS)  // 4096

__global__ void factorize_window(const float* __restrict__ w, float* __restrict__ ws) {
    if (threadIdx.x == 0) {
        float w000 = w[0];
        #pragma unroll
        for (int i = 0; i < 5; ++i) ws[i]      = w[i * 25];
        #pragma unroll
        for (int j = 0; j < 5; ++j) ws[5 + j]  = w[j * 5] / w000;
        #pragma unroll
        for (int k = 0; k < 5; ++k) ws[10 + k] = w[k] / w000;
    }
}

__launch_bounds__(128, 4)
__global__ void ssim_main(const float* __restrict__ img1,
                          const float* __restrict__ img2,
                          const float* __restrict__ wfac,
                          float* __restrict__ partials) {
    const int bid = blockIdx.x;
    const int ss  = bid & (NSS - 1);     // col half: 0 or 1
    const int idx = bid >> 1;
    const int th  = idx & (NHT - 1);
    const int td  = (idx >> 5) & (NDT - 1);
    const int b   = idx >> 9;

    const int h0 = th * TH, d0 = td * DSUB, cs = ss * SW;
    const float* __restrict__ x1 = img1 + (size_t)(b * 2 + 1) * NDIM * NDIM * NDIM;
    const float* __restrict__ x2 = img2 + (size_t)b * NDIM * NDIM * NDIM;

    float uW[5], vW[5], tW[5];
    #pragma unroll
    for (int i = 0; i < 5; ++i) { uW[i] = wfac[i]; vW[i] = wfac[5 + i]; tW[i] = wfac[10 + i]; }

    __shared__ float sWc[5][WR][SW];     // 10240 B; wave w owns cols [32w,32w+32)
    __shared__ float sRed[2];

    const int tid  = threadIdx.x;
    const int wv   = tid >> 6;           // wave id 0..1 -> 32-col stripe
    const int lane = tid & 63;
    const int sc   = wv * 32;            // block-local stripe col base
    // W-conv mapping (per wave, verbatim r8): 8 rows x 8 col-groups of 4
    const int wrow = lane >> 3;          // 0..7
    const int wg   = lane & 7;           // 0..7
    const int c0b  = sc + wg * 4;        // block-local col of 4 outputs
    const int c0g  = cs + c0b;           // global col (mult of 4, 0..124)
    const int ghw  = h0 + wrow - 2;
    // H/D mapping (per wave, verbatim r8): 4 rows x 16 col-pairs of 2
    const int orow = lane >> 4;          // 0..3
    const int ocb  = sc + (lane & 15) * 2;

    float2 ring[5][5];                   // [slot][field], static indices only
    float2 accS = make_float2(0.f, 0.f);

#define PHASE(I, P) do {                                                       \
    const int i_ = (I);                                                        \
    const int d_ = d0 - 2 + i_;                                                \
    float4 A0 = make_float4(0,0,0,0), A1 = A0, A2 = A0;                        \
    float4 B0 = A0, B1 = A0, B2 = A0;                                          \
    if (((unsigned)d_ < NDIM) && ((unsigned)ghw < NDIM)) {                     \
        const float* __restrict__ r1_ = x1 + ((size_t)d_ * NDIM + ghw) * NDIM; \
        const float* __restrict__ r2_ = x2 + ((size_t)d_ * NDIM + ghw) * NDIM; \
        if (c0g > 0)   { A0 = *(const float4*)(r1_ + c0g - 4);                 \
                         B0 = *(const float4*)(r2_ + c0g - 4); }               \
        A1 = *(const float4*)(r1_ + c0g);                                      \
        B1 = *(const float4*)(r2_ + c0g);                                      \
        if (c0g < 124) { A2 = *(const float4*)(r1_ + c0g + 4);                 \
                         B2 = *(const float4*)(r2_ + c0g + 4); }               \
    }                                                                          \
    float ra[12] = {A0.x,A0.y,A0.z,A0.w, A1.x,A1.y,A1.z,A1.w,                  \
                    A2.x,A2.y,A2.z,A2.w};                                      \
    float rb[12] = {B0.x,B0.y,B0.z,B0.w, B1.x,B1.y,B1.z,B1.w,                  \
                    B2.x,B2.y,B2.z,B2.w};                                      \
    float m1v[4], m2v[4], q11v[4], q22v[4], q12v[4];                           \
    _Pragma("unroll")                                                          \
    for (int k_ = 0; k_ < 4; ++k_) {                                           \
        float m1_=0.f, m2_=0.f, q11_=0.f, q22_=0.f, q12_=0.f;                  \
        _Pragma("unroll")                                                      \
        for (int c_ = 0; c_ < 5; ++c_) {                                       \
            const float a_ = ra[k_ + c_ + 2], b_ = rb[k_ + c_ + 2];            \
            const float ta_ = tW[c_] * a_, tb_ = tW[c_] * b_;                  \
            m1_ += ta_; m2_ += tb_;                                            \
            q11_ += ta_ * a_; q22_ += tb_ * b_; q12_ += ta_ * b_;              \
        }                                                                      \
        m1v[k_]=m1_; m2v[k_]=m2_; q11v[k_]=q11_; q22v[k_]=q22_; q12v[k_]=q12_; \
    }                                                                          \
    /* fence: prior phase's intra-wave LDS reads ordered before these writes;  \
       HW processes a wave's DS ops in issue order. Also the scheduling fence  \
       that prevents cross-phase load-hoist spills (r4-r6 lesson). */          \
    asm volatile("" ::: "memory");                                             \
    *(float4*)&sWc[0][wrow][c0b] = make_float4(m1v[0],m1v[1],m1v[2],m1v[3]);   \
    *(float4*)&sWc[1][wrow][c0b] = make_float4(m2v[0],m2v[1],m2v[2],m2v[3]);   \
    *(float4*)&sWc[2][wrow][c0b] = make_float4(q11v[0],q11v[1],q11v[2],q11v[3]);\
    *(float4*)&sWc[3][wrow][c0b] = make_float4(q22v[0],q22v[1],q22v[2],q22v[3]);\
    *(float4*)&sWc[4][wrow][c0b] = make_float4(q12v[0],q12v[1],q12v[2],q12v[3]);\
    asm volatile("" ::: "memory");  /* writes ordered before the reads below */\
    _Pragma("unroll")                                                          \
    for (int f_ = 0; f_ < 5; ++f_) {                                           \
        float2 F_ = make_float2(0.f, 0.f);                                     \
        _Pragma("unroll")                                                      \
        for (int r_ = 0; r_ < 5; ++r_) {                                       \
            const float2 wv_ = *(const float2*)&sWc[f_][orow + r_][ocb];       \
            F_.x += vW[r_] * wv_.x;                                            \
            F_.y += vW[r_] * wv_.y;                                            \
        }                                                                      \
        ring[(P)][f_] = F_;                                                    \
    }                                                                          \
    if (i_ >= 4) {                                                             \
        float2 F0 = make_float2(0,0), F1 = F0, F2 = F0, F3 = F0, F4 = F0;      \
        _Pragma("unroll")                                                      \
        for (int j_ = 0; j_ < 5; ++j_) {                                       \
            const int s_ = ((P) + 1 + j_) % 5;                                 \
            const float uw_ = uW[j_];                                          \
            F0.x += uw_*ring[s_][0].x; F0.y += uw_*ring[s_][0].y;              \
            F1.x += uw_*ring[s_][1].x; F1.y += uw_*ring[s_][1].y;              \
            F2.x += uw_*ring[s_][2].x; F2.y += uw_*ring[s_][2].y;              \
            F3.x += uw_*ring[s_][3].x; F3.y += uw_*ring[s_][3].y;              \
            F4.x += uw_*ring[s_][4].x; F4.y += uw_*ring[s_][4].y;              \
        }                                                                      \
        {                                                                      \
            const float mu1 = F0.x, mu2 = F1.x;                                \
            const float m11 = mu1*mu1, m22 = mu2*mu2, m12 = mu1*mu2;           \
            const float num = (2.f*m12 + 1e-4f) * (2.f*(F4.x - m12) + 9e-4f);  \
            const float den = (m11 + m22 + 1e-4f) *                            \
                              ((F2.x - m11) + (F3.x - m22) + 9e-4f);           \
            accS.x += __fdividef(num, den);                                    \
        }                                                                      \
        {                                                                      \
            const float mu1 = F0.y, mu2 = F1.y;                                \
            const float m11 = mu1*mu1, m22 = mu2*mu2, m12 = mu1*mu2;           \
            const float num = (2.f*m12 + 1e-4f) * (2.f*(F4.y - m12) + 9e-4f);  \
            const float den = (m11 + m22 + 1e-4f) *                            \
                              ((F2.y - m11) + (F3.y - m22) + 9e-4f);           \
            accS.y += __fdividef(num, den);                                    \
        }                                                                      \
    }                                                                          \
} while (0)

    // 12 slices: d0-2 .. d0+9. Prologue phases i=0,1 (literal -> D-conv
    // statically dead, minimal junction pressure), then the proven 5-phase
    // loop x2 with ring literals P = i mod 5 = {2,3,4,0,1}.
    PHASE(0, 0);
    PHASE(1, 1);
    for (int io = 0; io < 2; ++io) {
        const int ib = 2 + io * 5;
        PHASE(ib + 0, 2);
        PHASE(ib + 1, 3);
        PHASE(ib + 2, 4);
        PHASE(ib + 3, 0);
        PHASE(ib + 4, 1);
    }
#undef PHASE

    float acc = accS.x + accS.y;
    #pragma unroll
    for (int off = 32; off > 0; off >>= 1)
        acc += __shfl_down(acc, off, 64);
    if (lane == 0) sRed[wv] = acc;
    __syncthreads();                     // only cross-wave sync in the kernel
    if (tid == 0) partials[bid] = sRed[0] + sRed[1];
}

__global__ void finalize_kernel(const float* __restrict__ partials, float* __restrict__ out) {
    const int tid = threadIdx.x;
    double s = 0.0;
    for (int i = tid; i < NBLK; i += 256) s += (double)partials[i];
    #pragma unroll
    for (int off = 32; off > 0; off >>= 1)
        s += __shfl_down(s, off, 64);
    __shared__ double sm[4];
    if ((tid & 63) == 0) sm[tid >> 6] = s;
    __syncthreads();
    if (tid == 0)
        out[0] = 1.0f - (float)((sm[0] + sm[1] + sm[2] + sm[3]) / (double)(4LL * 128 * 128 * 128));
}

extern "C" void kernel_launch(void* const* d_in, const int* in_sizes, int n_in,
                              void* d_out, int out_size, void* d_ws, size_t ws_size,
                              hipStream_t stream) {
    const float* img1 = (const float*)d_in[0];   // (4,2,128,128,128) fp32
    const float* img2 = (const float*)d_in[1];   // (4,1,128,128,128) fp32
    const float* win  = (const float*)d_in[2];   // (1,1,5,5,5) fp32
    float* out = (float*)d_out;
    float* ws  = (float*)d_ws;
    float* wfac     = ws;         // 16 floats
    float* partials = ws + 16;    // NBLK floats, fully rewritten every launch

    hipLaunchKernelGGL(factorize_window, dim3(1), dim3(64), 0, stream, win, wfac);
    hipLaunchKernelGGL(ssim_main, dim3(NBLK), dim3(128), 0, stream, img1, img2, wfac, partials);
    hipLaunchKernelGGL(finalize_kernel, dim3(1), dim3(256), 0, stream, partials, out);
}

// Round 11
// 165.617 us; speedup vs baseline: 1.8521x; 1.8521x over previous
//
#include <hip/hip_runtime.h>

// SSIM 3D, round 14 = round 12 (DSUB=8, (256,2), clean codegen, 65KB writes,
// VGPR=72) + wave-uniform weights hoisted to SGPRs via readfirstlane.
// Session model (complete): VGPR cliff at 64 (m69: waves/SIMD halve above);
// body's natural demand in the 12-slice shape = 72 -> pin-to-64 spills (r13,
// 326MB), allow-72 keeps 4 waves/SIMD (r12, occupancy flat). The 15 uW/vW/tW
// weights are wave-uniform but vector-loaded -> live in VGPRs. v_fma_f32 can
// source one SGPR -> readfirstlane moves them to SGPRs at zero VALU cost,
// dropping demand to ~57-60 <= 64 -> 8 waves/SIMD eligible -> LDS-capped
// 7 blocks/CU = 28 waves/CU (vs 16 all session).
// Everything else verbatim r12 (all proven shapes):
//  - barrier-free wave-private LDS (wave owns 8 W-rows x 32-col stripe),
//    asm memory fences at the two former barrier sites (anti-hoist guard);
//  - 2x5-phase loop + 2-phase tail; plain partials tail + finalize kernel.
// Tripwires: VGPR_Count <= 64 (65+ => SGPR pressure defeated hoist => r8 is
// session ceiling); WRITE_SIZE < 1 MB (spill; VGPR_Count lies); occupancy up
// but dur flat => chain not TLP-coverable => r8 ceiling.
// Tile: W=128 (4 waves x 32 cols), TH=4 rows, DSUB=8 -> 2048 blocks.

#define NDIM 128
#define TH 4
#define WR (TH + 4)            // 8 W-conv rows
#define DSUB 8
#define NHT (NDIM / TH)        // 32
#define NDT (NDIM / DSUB)      // 16
#define NB 4
#define NBLK (NHT * NDT * NB)  // 2048

__global__ void factorize_window(const float* __restrict__ w, float* __restrict__ ws) {
    if (threadIdx.x == 0) {
        float w000 = w[0];
        #pragma unroll
        for (int i = 0; i < 5; ++i) ws[i]      = w[i * 25];
        #pragma unroll
        for (int j = 0; j < 5; ++j) ws[5 + j]  = w[j * 5] / w000;
        #pragma unroll
        for (int k = 0; k < 5; ++k) ws[10 + k] = w[k] / w000;
    }
}

__device__ __forceinline__ float uniform_f(float x) {
    return __int_as_float(__builtin_amdgcn_readfirstlane(__float_as_int(x)));
}

__launch_bounds__(256, 2)
__global__ void ssim_main(const float* __restrict__ img1,
                          const float* __restrict__ img2,
                          const float* __restrict__ wfac,
                          float* __restrict__ partials) {
    const int bid = blockIdx.x;
    const int th = bid % NHT;
    const int td = (bid / NHT) % NDT;
    const int b  = bid / (NHT * NDT);

    const int h0 = th * TH, d0 = td * DSUB;
    const float* __restrict__ x1 = img1 + (size_t)(b * 2 + 1) * NDIM * NDIM * NDIM;
    const float* __restrict__ x2 = img2 + (size_t)b * NDIM * NDIM * NDIM;

    // Wave-uniform weights -> SGPRs (readfirstlane). Frees ~15 VGPRs; VALU
    // instructions read them as the single allowed scalar operand.
    float uW[5], vW[5], tW[5];
    #pragma unroll
    for (int i = 0; i < 5; ++i) {
        uW[i] = uniform_f(wfac[i]);
        vW[i] = uniform_f(wfac[5 + i]);
        tW[i] = uniform_f(wfac[10 + i]);
    }

    __shared__ float sWc[5][WR][NDIM];   // 20 KB; wave w uses cols [32w,32w+32)
    __shared__ float sRed[4];

    const int tid  = threadIdx.x;
    const int wv   = tid >> 6;           // wave id 0..3 -> col stripe
    const int lane = tid & 63;
    const int sc   = wv * 32;            // stripe col base
    // W-conv mapping (per wave): 8 rows x 8 col-groups of 4
    const int wrow = lane >> 3;          // 0..7
    const int wg   = lane & 7;           // 0..7
    const int c0   = sc + wg * 4;        // global col of this lane's 4 outputs
    const int ghw  = h0 + wrow - 2;
    // H/D mapping (per wave): 4 rows x 16 col-pairs of 2
    const int orow = lane >> 4;          // 0..3
    const int oc   = sc + (lane & 15) * 2;

    float2 ring[5][5];                   // [slot][field], static indices only
    float2 accS = make_float2(0.f, 0.f);

#define PHASE(I, P) do {                                                       \
    const int i_ = (I);                                                        \
    const int d_ = d0 - 2 + i_;                                                \
    float4 A0 = make_float4(0,0,0,0), A1 = A0, A2 = A0;                        \
    float4 B0 = A0, B1 = A0, B2 = A0;                                          \
    if (((unsigned)d_ < NDIM) && ((unsigned)ghw < NDIM)) {                     \
        const float* __restrict__ r1_ = x1 + ((size_t)d_ * NDIM + ghw) * NDIM; \
        const float* __restrict__ r2_ = x2 + ((size_t)d_ * NDIM + ghw) * NDIM; \
        if (c0 > 0)   { A0 = *(const float4*)(r1_ + c0 - 4);                   \
                        B0 = *(const float4*)(r2_ + c0 - 4); }                 \
        A1 = *(const float4*)(r1_ + c0);                                       \
        B1 = *(const float4*)(r2_ + c0);                                       \
        if (c0 < 124) { A2 = *(const float4*)(r1_ + c0 + 4);                   \
                        B2 = *(const float4*)(r2_ + c0 + 4); }                 \
    }                                                                          \
    float ra[12] = {A0.x,A0.y,A0.z,A0.w, A1.x,A1.y,A1.z,A1.w,                  \
                    A2.x,A2.y,A2.z,A2.w};                                      \
    float rb[12] = {B0.x,B0.y,B0.z,B0.w, B1.x,B1.y,B1.z,B1.w,                  \
                    B2.x,B2.y,B2.z,B2.w};                                      \
    float m1v[4], m2v[4], q11v[4], q22v[4], q12v[4];                           \
    _Pragma("unroll")                                                          \
    for (int k_ = 0; k_ < 4; ++k_) {                                           \
        float m1_=0.f, m2_=0.f, q11_=0.f, q22_=0.f, q12_=0.f;                  \
        _Pragma("unroll")                                                      \
        for (int c_ = 0; c_ < 5; ++c_) {                                       \
            const float a_ = ra[k_ + c_ + 2], b_ = rb[k_ + c_ + 2];            \
            const float ta_ = tW[c_] * a_, tb_ = tW[c_] * b_;                  \
            m1_ += ta_; m2_ += tb_;                                            \
            q11_ += ta_ * a_; q22_ += tb_ * b_; q12_ += ta_ * b_;              \
        }                                                                      \
        m1v[k_]=m1_; m2v[k_]=m2_; q11v[k_]=q11_; q22v[k_]=q22_; q12v[k_]=q12_; \
    }                                                                          \
    /* fence: prior phase's intra-wave LDS reads ordered before these writes;  \
       HW processes a wave's DS ops in issue order. Also the scheduling fence  \
       that prevents cross-phase load-hoist spills (r4-r6 lesson). */          \
    asm volatile("" ::: "memory");                                             \
    *(float4*)&sWc[0][wrow][c0] = make_float4(m1v[0],m1v[1],m1v[2],m1v[3]);    \
    *(float4*)&sWc[1][wrow][c0] = make_float4(m2v[0],m2v[1],m2v[2],m2v[3]);    \
    *(float4*)&sWc[2][wrow][c0] = make_float4(q11v[0],q11v[1],q11v[2],q11v[3]);\
    *(float4*)&sWc[3][wrow][c0] = make_float4(q22v[0],q22v[1],q22v[2],q22v[3]);\
    *(float4*)&sWc[4][wrow][c0] = make_float4(q12v[0],q12v[1],q12v[2],q12v[3]);\
    asm volatile("" ::: "memory");  /* writes ordered before the reads below */\
    _Pragma("unroll")                                                          \
    for (int f_ = 0; f_ < 5; ++f_) {                                           \
        float2 F_ = make_float2(0.f, 0.f);                                     \
        _Pragma("unroll")                                                      \
        for (int r_ = 0; r_ < 5; ++r_) {                                       \
            const float2 wv_ = *(const float2*)&sWc[f_][orow + r_][oc];        \
            F_.x += vW[r_] * wv_.x;                                            \
            F_.y += vW[r_] * wv_.y;                                            \
        }                                                                      \
        ring[(P)][f_] = F_;                                                    \
    }                                                                          \
    if (i_ >= 4) {                                                             \
        float2 F0 = make_float2(0,0), F1 = F0, F2 = F0, F3 = F0, F4 = F0;      \
        _Pragma("unroll")                                                      \
        for (int j_ = 0; j_ < 5; ++j_) {                                       \
            const int s_ = ((P) + 1 + j_) % 5;                                 \
            const float uw_ = uW[j_];                                          \
            F0.x += uw_*ring[s_][0].x; F0.y += uw_*ring[s_][0].y;              \
            F1.x += uw_*ring[s_][1].x; F1.y += uw_*ring[s_][1].y;              \
            F2.x += uw_*ring[s_][2].x; F2.y += uw_*ring[s_][2].y;              \
            F3.x += uw_*ring[s_][3].x; F3.y += uw_*ring[s_][3].y;              \
            F4.x += uw_*ring[s_][4].x; F4.y += uw_*ring[s_][4].y;              \
        }                                                                      \
        {                                                                      \
            const float mu1 = F0.x, mu2 = F1.x;                                \
            const float m11 = mu1*mu1, m22 = mu2*mu2, m12 = mu1*mu2;           \
            const float num = (2.f*m12 + 1e-4f) * (2.f*(F4.x - m12) + 9e-4f);  \
            const float den = (m11 + m22 + 1e-4f) *                            \
                              ((F2.x - m11) + (F3.x - m22) + 9e-4f);           \
            accS.x += __fdividef(num, den);                                    \
        }                                                                      \
        {                                                                      \
            const float mu1 = F0.y, mu2 = F1.y;                                \
            const float m11 = mu1*mu1, m22 = mu2*mu2, m12 = mu1*mu2;           \
            const float num = (2.f*m12 + 1e-4f) * (2.f*(F4.y - m12) + 9e-4f);  \
            const float den = (m11 + m22 + 1e-4f) *                            \
                              ((F2.y - m11) + (F3.y - m22) + 9e-4f);           \
            accS.y += __fdividef(num, den);                                    \
        }                                                                      \
    }                                                                          \
} while (0)

    // 12 slices: d0-2 .. d0+9. Proven 5-phase loop region x2 + 2-phase tail
    // (r12 shape: compiled clean, 65KB writes).
    for (int io = 0; io < 2; ++io) {
        const int ib = io * 5;
        PHASE(ib + 0, 0);
        PHASE(ib + 1, 1);
        PHASE(ib + 2, 2);
        PHASE(ib + 3, 3);
        PHASE(ib + 4, 4);
    }
    PHASE(10, 0);
    PHASE(11, 1);
#undef PHASE

    float acc = accS.x + accS.y;
    #pragma unroll
    for (int off = 32; off > 0; off >>= 1)
        acc += __shfl_down(acc, off, 64);
    __syncthreads();                     // only cross-wave sync in the kernel
    if (lane == 0) sRed[wv] = acc;
    __syncthreads();
    if (tid == 0) partials[bid] = sRed[0] + sRed[1] + sRed[2] + sRed[3];
}

__global__ void finalize_kernel(const float* __restrict__ partials, float* __restrict__ out) {
    const int tid = threadIdx.x;
    double s = 0.0;
    for (int i = tid; i < NBLK; i += 256) s += (double)partials[i];
    #pragma unroll
    for (int off = 32; off > 0; off >>= 1)
        s += __shfl_down(s, off, 64);
    __shared__ double sm[4];
    if ((tid & 63) == 0) sm[tid >> 6] = s;
    __syncthreads();
    if (tid == 0)
        out[0] = 1.0f - (float)((sm[0] + sm[1] + sm[2] + sm[3]) / (double)(4LL * 128 * 128 * 128));
}

extern "C" void kernel_launch(void* const* d_in, const int* in_sizes, int n_in,
                              void* d_out, int out_size, void* d_ws, size_t ws_size,
                              hipStream_t stream) {
    const float* img1 = (const float*)d_in[0];   // (4,2,128,128,128) fp32
    const float* img2 = (const float*)d_in[1];   // (4,1,128,128,128) fp32
    const float* win  = (const float*)d_in[2];   // (1,1,5,5,5) fp32
    float* out = (float*)d_out;
    float* ws  = (float*)d_ws;
    float* wfac     = ws;         // 16 floats
    float* partials = ws + 16;    // NBLK floats, fully rewritten every launch

    hipLaunchKernelGGL(factorize_window, dim3(1), dim3(64), 0, stream, win, wfac);
    hipLaunchKernelGGL(ssim_main, dim3(NBLK), dim3(256), 0, stream, img1, img2, wfac, partials);
    hipLaunchKernelGGL(finalize_kernel, dim3(1), dim3(256), 0, stream, partials, out);
}

// Round 12
// 160.529 us; speedup vs baseline: 1.9108x; 1.0317x over previous
//
#include <hip/hip_runtime.h>

// SSIM 3D, round 15 = round 12 (DSUB=8, (256,2), proven-clean codegen) with a
// 4-FIELD algebraic reduction replacing the 5-field pipeline.
// Key identity: SSIM needs only mu1, mu2, q12, and qs = q11+q22:
//   den = (m11+m22+C1) * (qs - (m11+m22) + C2)
//   num = (2*m12+C1) * (2*(q12-m12) + C2)
// Convolution is linear -> carry qs as ONE field through W->H->D.
// Effects: ring 50->40 VGPR, W-accum -2, H-temps -1 => natural demand
// ~72-12 = 58-62 <= 64 cliff (m69) -> 8 waves/SIMD eligible. LDS 20.5->16.4KB.
// Grid 2048 = 8 blocks/CU exact = 32 waves/CU (vs 16 all session). Plus 20%
// fewer H/D LDS reads + FMAs (the serial chain shrinks too).
// Everything else verbatim r12 (proven shapes):
//  - barrier-free wave-private LDS (wave owns 8 W-rows x 32-col stripe),
//    asm memory fences at the two former barrier sites (anti-hoist guard);
//  - 2x5-phase loop + 2-phase tail; plain partials tail + finalize kernel;
//  - __launch_bounds__(256,2) (cap 128; r11/r12 proven no-spill regime).
// Tripwires: VGPR_Count <= 64 (>=65 => occupancy door closed => declare r8
// ceiling); WRITE_SIZE < 1 MB (spill detector; VGPR_Count lies); VGPR ok but
// dur flat => chain not TLP-coverable => declare.
// Tile: W=128 (4 waves x 32 cols), TH=4 rows, DSUB=8 -> 2048 blocks.

#define NDIM 128
#define TH 4
#define WR (TH + 4)            // 8 W-conv rows
#define DSUB 8
#define NHT (NDIM / TH)        // 32
#define NDT (NDIM / DSUB)      // 16
#define NB 4
#define NBLK (NHT * NDT * NB)  // 2048

__global__ void factorize_window(const float* __restrict__ w, float* __restrict__ ws) {
    if (threadIdx.x == 0) {
        float w000 = w[0];
        #pragma unroll
        for (int i = 0; i < 5; ++i) ws[i]      = w[i * 25];
        #pragma unroll
        for (int j = 0; j < 5; ++j) ws[5 + j]  = w[j * 5] / w000;
        #pragma unroll
        for (int k = 0; k < 5; ++k) ws[10 + k] = w[k] / w000;
    }
}

__launch_bounds__(256, 2)
__global__ void ssim_main(const float* __restrict__ img1,
                          const float* __restrict__ img2,
                          const float* __restrict__ wfac,
                          float* __restrict__ partials) {
    const int bid = blockIdx.x;
    const int th = bid % NHT;
    const int td = (bid / NHT) % NDT;
    const int b  = bid / (NHT * NDT);

    const int h0 = th * TH, d0 = td * DSUB;
    const float* __restrict__ x1 = img1 + (size_t)(b * 2 + 1) * NDIM * NDIM * NDIM;
    const float* __restrict__ x2 = img2 + (size_t)b * NDIM * NDIM * NDIM;

    float uW[5], vW[5], tW[5];
    #pragma unroll
    for (int i = 0; i < 5; ++i) { uW[i] = wfac[i]; vW[i] = wfac[5 + i]; tW[i] = wfac[10 + i]; }

    __shared__ float sWc[4][WR][NDIM];   // 16 KB; wave w uses cols [32w,32w+32)
    __shared__ float sRed[4];

    const int tid  = threadIdx.x;
    const int wv   = tid >> 6;           // wave id 0..3 -> col stripe
    const int lane = tid & 63;
    const int sc   = wv * 32;            // stripe col base
    // W-conv mapping (per wave): 8 rows x 8 col-groups of 4
    const int wrow = lane >> 3;          // 0..7
    const int wg   = lane & 7;           // 0..7
    const int c0   = sc + wg * 4;        // global col of this lane's 4 outputs
    const int ghw  = h0 + wrow - 2;
    // H/D mapping (per wave): 4 rows x 16 col-pairs of 2
    const int orow = lane >> 4;          // 0..3
    const int oc   = sc + (lane & 15) * 2;

    float2 ring[5][4];                   // [slot][field: m1,m2,qs,q12]
    float2 accS = make_float2(0.f, 0.f);

#define PHASE(I, P) do {                                                       \
    const int i_ = (I);                                                        \
    const int d_ = d0 - 2 + i_;                                                \
    float4 A0 = make_float4(0,0,0,0), A1 = A0, A2 = A0;                        \
    float4 B0 = A0, B1 = A0, B2 = A0;                                          \
    if (((unsigned)d_ < NDIM) && ((unsigned)ghw < NDIM)) {                     \
        const float* __restrict__ r1_ = x1 + ((size_t)d_ * NDIM + ghw) * NDIM; \
        const float* __restrict__ r2_ = x2 + ((size_t)d_ * NDIM + ghw) * NDIM; \
        if (c0 > 0)   { A0 = *(const float4*)(r1_ + c0 - 4);                   \
                        B0 = *(const float4*)(r2_ + c0 - 4); }                 \
        A1 = *(const float4*)(r1_ + c0);                                       \
        B1 = *(const float4*)(r2_ + c0);                                       \
        if (c0 < 124) { A2 = *(const float4*)(r1_ + c0 + 4);                   \
                        B2 = *(const float4*)(r2_ + c0 + 4); }                 \
    }                                                                          \
    float ra[12] = {A0.x,A0.y,A0.z,A0.w, A1.x,A1.y,A1.z,A1.w,                  \
                    A2.x,A2.y,A2.z,A2.w};                                      \
    float rb[12] = {B0.x,B0.y,B0.z,B0.w, B1.x,B1.y,B1.z,B1.w,                  \
                    B2.x,B2.y,B2.z,B2.w};                                      \
    float m1v[4], m2v[4], qsv[4], q12v[4];                                     \
    _Pragma("unroll")                                                          \
    for (int k_ = 0; k_ < 4; ++k_) {                                           \
        float m1_=0.f, m2_=0.f, qs_=0.f, q12_=0.f;                             \
        _Pragma("unroll")                                                      \
        for (int c_ = 0; c_ < 5; ++c_) {                                       \
            const float a_ = ra[k_ + c_ + 2], b_ = rb[k_ + c_ + 2];            \
            const float ta_ = tW[c_] * a_, tb_ = tW[c_] * b_;                  \
            m1_ += ta_; m2_ += tb_;                                            \
            qs_ += ta_ * a_ + tb_ * b_; q12_ += ta_ * b_;                      \
        }                                                                      \
        m1v[k_]=m1_; m2v[k_]=m2_; qsv[k_]=qs_; q12v[k_]=q12_;                  \
    }                                                                          \
    /* fence: prior phase's intra-wave LDS reads ordered before these writes;  \
       HW processes a wave's DS ops in issue order. Also the scheduling fence  \
       that prevents cross-phase load-hoist spills (r4-r6 lesson). */          \
    asm volatile("" ::: "memory");                                             \
    *(float4*)&sWc[0][wrow][c0] = make_float4(m1v[0],m1v[1],m1v[2],m1v[3]);    \
    *(float4*)&sWc[1][wrow][c0] = make_float4(m2v[0],m2v[1],m2v[2],m2v[3]);    \
    *(float4*)&sWc[2][wrow][c0] = make_float4(qsv[0],qsv[1],qsv[2],qsv[3]);    \
    *(float4*)&sWc[3][wrow][c0] = make_float4(q12v[0],q12v[1],q12v[2],q12v[3]);\
    asm volatile("" ::: "memory");  /* writes ordered before the reads below */\
    _Pragma("unroll")                                                          \
    for (int f_ = 0; f_ < 4; ++f_) {                                           \
        float2 F_ = make_float2(0.f, 0.f);                                     \
        _Pragma("unroll")                                                      \
        for (int r_ = 0; r_ < 5; ++r_) {                                       \
            const float2 wv_ = *(const float2*)&sWc[f_][orow + r_][oc];        \
            F_.x += vW[r_] * wv_.x;                                            \
            F_.y += vW[r_] * wv_.y;                                            \
        }                                                                      \
        ring[(P)][f_] = F_;                                                    \
    }                                                                          \
    if (i_ >= 4) {                                                             \
        float2 F0 = make_float2(0,0), F1 = F0, F2 = F0, F3 = F0;               \
        _Pragma("unroll")                                                      \
        for (int j_ = 0; j_ < 5; ++j_) {                                       \
            const int s_ = ((P) + 1 + j_) % 5;                                 \
            const float uw_ = uW[j_];                                          \
            F0.x += uw_*ring[s_][0].x; F0.y += uw_*ring[s_][0].y;              \
            F1.x += uw_*ring[s_][1].x; F1.y += uw_*ring[s_][1].y;              \
            F2.x += uw_*ring[s_][2].x; F2.y += uw_*ring[s_][2].y;              \
            F3.x += uw_*ring[s_][3].x; F3.y += uw_*ring[s_][3].y;              \
        }                                                                      \
        {                                                                      \
            const float mu1 = F0.x, mu2 = F1.x;                                \
            const float m11 = mu1*mu1, m22 = mu2*mu2, m12 = mu1*mu2;           \
            const float ms  = m11 + m22;                                       \
            const float num = (2.f*m12 + 1e-4f) * (2.f*(F3.x - m12) + 9e-4f);  \
            const float den = (ms + 1e-4f) * ((F2.x - ms) + 9e-4f);            \
            accS.x += __fdividef(num, den);                                    \
        }                                                                      \
        {                                                                      \
            const float mu1 = F0.y, mu2 = F1.y;                                \
            const float m11 = mu1*mu1, m22 = mu2*mu2, m12 = mu1*mu2;           \
            const float ms  = m11 + m22;                                       \
            const float num = (2.f*m12 + 1e-4f) * (2.f*(F3.y - m12) + 9e-4f);  \
            const float den = (ms + 1e-4f) * ((F2.y - ms) + 9e-4f);            \
            accS.y += __fdividef(num, den);                                    \
        }                                                                      \
    }                                                                          \
} while (0)

    // 12 slices: d0-2 .. d0+9. Proven 5-phase loop region x2 + 2-phase tail
    // (r12 shape: compiled clean, 65KB writes).
    for (int io = 0; io < 2; ++io) {
        const int ib = io * 5;
        PHASE(ib + 0, 0);
        PHASE(ib + 1, 1);
        PHASE(ib + 2, 2);
        PHASE(ib + 3, 3);
        PHASE(ib + 4, 4);
    }
    PHASE(10, 0);
    PHASE(11, 1);
#undef PHASE

    float acc = accS.x + accS.y;
    #pragma unroll
    for (int off = 32; off > 0; off >>= 1)
        acc += __shfl_down(acc, off, 64);
    __syncthreads();                     // only cross-wave sync in the kernel
    if (lane == 0) sRed[wv] = acc;
    __syncthreads();
    if (tid == 0) partials[bid] = sRed[0] + sRed[1] + sRed[2] + sRed[3];
}

__global__ void finalize_kernel(const float* __restrict__ partials, float* __restrict__ out) {
    const int tid = threadIdx.x;
    double s = 0.0;
    for (int i = tid; i < NBLK; i += 256) s += (double)partials[i];
    #pragma unroll
    for (int off = 32; off > 0; off >>= 1)
        s += __shfl_down(s, off, 64);
    __shared__ double sm[4];
    if ((tid & 63) == 0) sm[tid >> 6] = s;
    __syncthreads();
    if (tid == 0)
        out[0] = 1.0f - (float)((sm[0] + sm[1] + sm[2] + sm[3]) / (double)(4LL * 128 * 128 * 128));
}

extern "C" void kernel_launch(void* const* d_in, const int* in_sizes, int n_in,
                              void* d_out, int out_size, void* d_ws, size_t ws_size,
                              hipStream_t stream) {
    const float* img1 = (const float*)d_in[0];   // (4,2,128,128,128) fp32
    const float* img2 = (const float*)d_in[1];   // (4,1,128,128,128) fp32
    const float* win  = (const float*)d_in[2];   // (1,1,5,5,5) fp32
    float* out = (float*)d_out;
    float* ws  = (float*)d_ws;
    float* wfac     = ws;         // 16 floats
    float* partials = ws + 16;    // NBLK floats, fully rewritten every launch

    hipLaunchKernelGGL(factorize_window, dim3(1), dim3(64), 0, stream, win, wfac);
    hipLaunchKernelGGL(ssim_main, dim3(NBLK), dim3(256), 0, stream, img1, img2, wfac, partials);
    hipLaunchKernelGGL(finalize_kernel, dim3(1), dim3(256), 0, stream, partials, out);
}

// Round 13
// 151.648 us; speedup vs baseline: 2.0227x; 1.0586x over previous
//
#include <hip/hip_runtime.h>

// SSIM 3D, round 16 = round 15 (4-field qs-reduction, DSUB=8, (256,2), clean
// codegen, VGPR=68) + SYMMETRIC-WINDOW weight compression 15 -> 9 regs.
// The Gaussian window is exactly symmetric (c = arange(5)-2; positions +-2 /
// +-1 are bit-identical), so uW[0]==uW[4], uW[1]==uW[3] on every axis.
// Pair-sum form t0*(x0+x4) + t1*(x1+x3) + t2*x2 in W, H, and D stages:
// same-or-fewer FLOPs, zero extra temp pressure, -6 persistent VGPRs.
// Register account at the persistent point: ring 40 + accS 2 + weights 9 +
// addressing ~8 = ~60 <= 64 cliff (m69) -> 8 waves/SIMD eligible.
// LDS 16.9 KB -> 9 blocks/CU allowed; grid 2048 = 8 blocks/CU exact =
// 32 waves/CU (2x the 16 waves/CU every round so far has been stuck at).
// Everything else verbatim r15 (all proven shapes):
//  - barrier-free wave-private LDS (wave owns 8 W-rows x 32-col stripe),
//    asm memory fences at the two former barrier sites (anti-hoist guard);
//  - 2x5-phase loop + 2-phase tail; plain partials tail + finalize kernel;
//  - __launch_bounds__(256,2) (proven no-spill regime).
// Tripwires: VGPR_Count <= 64 (>=65 => last principled cut failed => declare
// r15 ceiling next round); WRITE_SIZE < 1 MB (spill detector; VGPR_Count
// lies); VGPR ok but dur flat => chain not TLP-coverable => declare.
// Tile: W=128 (4 waves x 32 cols), TH=4 rows, DSUB=8 -> 2048 blocks.

#define NDIM 128
#define TH 4
#define WR (TH + 4)            // 8 W-conv rows
#define DSUB 8
#define NHT (NDIM / TH)        // 32
#define NDT (NDIM / DSUB)      // 16
#define NB 4
#define NBLK (NHT * NDT * NB)  // 2048

__global__ void factorize_window(const float* __restrict__ w, float* __restrict__ ws) {
    if (threadIdx.x == 0) {
        float w000 = w[0];
        // symmetric rank-1 factors: only taps 0,1,2 needed (3==1, 4==0)
        #pragma unroll
        for (int i = 0; i < 3; ++i) ws[i]     = w[i * 25];          // u0,u1,u2
        #pragma unroll
        for (int j = 0; j < 3; ++j) ws[3 + j] = w[j * 5] / w000;    // v0,v1,v2
        #pragma unroll
        for (int k = 0; k < 3; ++k) ws[6 + k] = w[k] / w000;        // t0,t1,t2
    }
}

__launch_bounds__(256, 2)
__global__ void ssim_main(const float* __restrict__ img1,
                          const float* __restrict__ img2,
                          const float* __restrict__ wfac,
                          float* __restrict__ partials) {
    const int bid = blockIdx.x;
    const int th = bid % NHT;
    const int td = (bid / NHT) % NDT;
    const int b  = bid / (NHT * NDT);

    const int h0 = th * TH, d0 = td * DSUB;
    const float* __restrict__ x1 = img1 + (size_t)(b * 2 + 1) * NDIM * NDIM * NDIM;
    const float* __restrict__ x2 = img2 + (size_t)b * NDIM * NDIM * NDIM;

    float uW[3], vW[3], tW[3];
    #pragma unroll
    for (int i = 0; i < 3; ++i) { uW[i] = wfac[i]; vW[i] = wfac[3 + i]; tW[i] = wfac[6 + i]; }

    __shared__ float sWc[4][WR][NDIM];   // 16 KB; wave w uses cols [32w,32w+32)
    __shared__ float sRed[4];

    const int tid  = threadIdx.x;
    const int wv   = tid >> 6;           // wave id 0..3 -> col stripe
    const int lane = tid & 63;
    const int sc   = wv * 32;            // stripe col base
    // W-conv mapping (per wave): 8 rows x 8 col-groups of 4
    const int wrow = lane >> 3;          // 0..7
    const int wg   = lane & 7;           // 0..7
    const int c0   = sc + wg * 4;        // global col of this lane's 4 outputs
    const int ghw  = h0 + wrow - 2;
    // H/D mapping (per wave): 4 rows x 16 col-pairs of 2
    const int orow = lane >> 4;          // 0..3
    const int oc   = sc + (lane & 15) * 2;

    float2 ring[5][4];                   // [slot][field: m1,m2,qs,q12]
    float2 accS = make_float2(0.f, 0.f);

#define PHASE(I, P) do {                                                       \
    const int i_ = (I);                                                        \
    const int d_ = d0 - 2 + i_;                                                \
    float4 A0 = make_float4(0,0,0,0), A1 = A0, A2 = A0;                        \
    float4 B0 = A0, B1 = A0, B2 = A0;                                          \
    if (((unsigned)d_ < NDIM) && ((unsigned)ghw < NDIM)) {                     \
        const float* __restrict__ r1_ = x1 + ((size_t)d_ * NDIM + ghw) * NDIM; \
        const float* __restrict__ r2_ = x2 + ((size_t)d_ * NDIM + ghw) * NDIM; \
        if (c0 > 0)   { A0 = *(const float4*)(r1_ + c0 - 4);                   \
                        B0 = *(const float4*)(r2_ + c0 - 4); }                 \
        A1 = *(const float4*)(r1_ + c0);                                       \
        B1 = *(const float4*)(r2_ + c0);                                       \
        if (c0 < 124) { A2 = *(const float4*)(r1_ + c0 + 4);                   \
                        B2 = *(const float4*)(r2_ + c0 + 4); }                 \
    }                                                                          \
    float ra[12] = {A0.x,A0.y,A0.z,A0.w, A1.x,A1.y,A1.z,A1.w,                  \
                    A2.x,A2.y,A2.z,A2.w};                                      \
    float rb[12] = {B0.x,B0.y,B0.z,B0.w, B1.x,B1.y,B1.z,B1.w,                  \
                    B2.x,B2.y,B2.z,B2.w};                                      \
    float m1v[4], m2v[4], qsv[4], q12v[4];                                     \
    _Pragma("unroll")                                                          \
    for (int k_ = 0; k_ < 4; ++k_) {                                           \
        const float a0_=ra[k_+2], a1_=ra[k_+3], a2_=ra[k_+4],                  \
                    a3_=ra[k_+5], a4_=ra[k_+6];                                \
        const float b0_=rb[k_+2], b1_=rb[k_+3], b2_=rb[k_+4],                  \
                    b3_=rb[k_+5], b4_=rb[k_+6];                                \
        /* symmetric taps: tW[0]*(x0+x4) + tW[1]*(x1+x3) + tW[2]*x2 */         \
        m1v[k_]  = tW[0]*(a0_+a4_) + tW[1]*(a1_+a3_) + tW[2]*a2_;              \
        m2v[k_]  = tW[0]*(b0_+b4_) + tW[1]*(b1_+b3_) + tW[2]*b2_;              \
        const float qp0 = a0_*a0_ + b0_*b0_ + a4_*a4_ + b4_*b4_;               \
        const float qp1 = a1_*a1_ + b1_*b1_ + a3_*a3_ + b3_*b3_;               \
        const float qp2 = a2_*a2_ + b2_*b2_;                                   \
        qsv[k_]  = tW[0]*qp0 + tW[1]*qp1 + tW[2]*qp2;                          \
        const float pp0 = a0_*b0_ + a4_*b4_;                                   \
        const float pp1 = a1_*b1_ + a3_*b3_;                                   \
        q12v[k_] = tW[0]*pp0 + tW[1]*pp1 + tW[2]*(a2_*b2_);                    \
    }                                                                          \
    /* fence: prior phase's intra-wave LDS reads ordered before these writes;  \
       HW processes a wave's DS ops in issue order. Also the scheduling fence  \
       that prevents cross-phase load-hoist spills (r4-r6 lesson). */          \
    asm volatile("" ::: "memory");                                             \
    *(float4*)&sWc[0][wrow][c0] = make_float4(m1v[0],m1v[1],m1v[2],m1v[3]);    \
    *(float4*)&sWc[1][wrow][c0] = make_float4(m2v[0],m2v[1],m2v[2],m2v[3]);    \
    *(float4*)&sWc[2][wrow][c0] = make_float4(qsv[0],qsv[1],qsv[2],qsv[3]);    \
    *(float4*)&sWc[3][wrow][c0] = make_float4(q12v[0],q12v[1],q12v[2],q12v[3]);\
    asm volatile("" ::: "memory");  /* writes ordered before the reads below */\
    _Pragma("unroll")                                                          \
    for (int f_ = 0; f_ < 4; ++f_) {                                           \
        const float2 r0_ = *(const float2*)&sWc[f_][orow + 0][oc];             \
        const float2 r1_ = *(const float2*)&sWc[f_][orow + 1][oc];             \
        const float2 r2_ = *(const float2*)&sWc[f_][orow + 2][oc];             \
        const float2 r3_ = *(const float2*)&sWc[f_][orow + 3][oc];             \
        const float2 r4_ = *(const float2*)&sWc[f_][orow + 4][oc];             \
        float2 F_;                                                             \
        F_.x = vW[0]*(r0_.x+r4_.x) + vW[1]*(r1_.x+r3_.x) + vW[2]*r2_.x;        \
        F_.y = vW[0]*(r0_.y+r4_.y) + vW[1]*(r1_.y+r3_.y) + vW[2]*r2_.y;        \
        ring[(P)][f_] = F_;                                                    \
    }                                                                          \
    if (i_ >= 4) {                                                             \
        /* D-conv, symmetric: slots sA..sE = oldest..newest */                 \
        const int sA = ((P) + 1) % 5, sB = ((P) + 2) % 5, sC = ((P) + 3) % 5,  \
                  sD = ((P) + 4) % 5, sE = (P);                                \
        float2 F0, F1, F2, F3;                                                 \
        F0.x = uW[0]*(ring[sA][0].x+ring[sE][0].x)                             \
             + uW[1]*(ring[sB][0].x+ring[sD][0].x) + uW[2]*ring[sC][0].x;      \
        F0.y = uW[0]*(ring[sA][0].y+ring[sE][0].y)                             \
             + uW[1]*(ring[sB][0].y+ring[sD][0].y) + uW[2]*ring[sC][0].y;      \
        F1.x = uW[0]*(ring[sA][1].x+ring[sE][1].x)                             \
             + uW[1]*(ring[sB][1].x+ring[sD][1].x) + uW[2]*ring[sC][1].x;      \
        F1.y = uW[0]*(ring[sA][1].y+ring[sE][1].y)                             \
             + uW[1]*(ring[sB][1].y+ring[sD][1].y) + uW[2]*ring[sC][1].y;      \
        F2.x = uW[0]*(ring[sA][2].x+ring[sE][2].x)                             \
             + uW[1]*(ring[sB][2].x+ring[sD][2].x) + uW[2]*ring[sC][2].x;      \
        F2.y = uW[0]*(ring[sA][2].y+ring[sE][2].y)                             \
             + uW[1]*(ring[sB][2].y+ring[sD][2].y) + uW[2]*ring[sC][2].y;      \
        F3.x = uW[0]*(ring[sA][3].x+ring[sE][3].x)                             \
             + uW[1]*(ring[sB][3].x+ring[sD][3].x) + uW[2]*ring[sC][3].x;      \
        F3.y = uW[0]*(ring[sA][3].y+ring[sE][3].y)                             \
             + uW[1]*(ring[sB][3].y+ring[sD][3].y) + uW[2]*ring[sC][3].y;      \
        {                                                                      \
            const float mu1 = F0.x, mu2 = F1.x;                                \
            const float m11 = mu1*mu1, m22 = mu2*mu2, m12 = mu1*mu2;           \
            const float ms  = m11 + m22;                                       \
            const float num = (2.f*m12 + 1e-4f) * (2.f*(F3.x - m12) + 9e-4f);  \
            const float den = (ms + 1e-4f) * ((F2.x - ms) + 9e-4f);            \
            accS.x += __fdividef(num, den);                                    \
        }                                                                      \
        {                                                                      \
            const float mu1 = F0.y, mu2 = F1.y;                                \
            const float m11 = mu1*mu1, m22 = mu2*mu2, m12 = mu1*mu2;           \
            const float ms  = m11 + m22;                                       \
            const float num = (2.f*m12 + 1e-4f) * (2.f*(F3.y - m12) + 9e-4f);  \
            const float den = (ms + 1e-4f) * ((F2.y - ms) + 9e-4f);            \
            accS.y += __fdividef(num, den);                                    \
        }                                                                      \
    }                                                                          \
} while (0)

    // 12 slices: d0-2 .. d0+9. Proven 5-phase loop region x2 + 2-phase tail
    // (r12/r15 shape: compiled clean, 64KB writes).
    for (int io = 0; io < 2; ++io) {
        const int ib = io * 5;
        PHASE(ib + 0, 0);
        PHASE(ib + 1, 1);
        PHASE(ib + 2, 2);
        PHASE(ib + 3, 3);
        PHASE(ib + 4, 4);
    }
    PHASE(10, 0);
    PHASE(11, 1);
#undef PHASE

    float acc = accS.x + accS.y;
    #pragma unroll
    for (int off = 32; off > 0; off >>= 1)
        acc += __shfl_down(acc, off, 64);
    __syncthreads();                     // only cross-wave sync in the kernel
    if (lane == 0) sRed[wv] = acc;
    __syncthreads();
    if (tid == 0) partials[bid] = sRed[0] + sRed[1] + sRed[2] + sRed[3];
}

__global__ void finalize_kernel(const float* __restrict__ partials, float* __restrict__ out) {
    const int tid = threadIdx.x;
    double s = 0.0;
    for (int i = tid; i < NBLK; i += 256) s += (double)partials[i];
    #pragma unroll
    for (int off = 32; off > 0; off >>= 1)
        s += __shfl_down(s, off, 64);
    __shared__ double sm[4];
    if ((tid & 63) == 0) sm[tid >> 6] = s;
    __syncthreads();
    if (tid == 0)
        out[0] = 1.0f - (float)((sm[0] + sm[1] + sm[2] + sm[3]) / (double)(4LL * 128 * 128 * 128));
}

extern "C" void kernel_launch(void* const* d_in, const int* in_sizes, int n_in,
                              void* d_out, int out_size, void* d_ws, size_t ws_size,
                              hipStream_t stream) {
    const float* img1 = (const float*)d_in[0];   // (4,2,128,128,128) fp32
    const float* img2 = (const float*)d_in[1];   // (4,1,128,128,128) fp32
    const float* win  = (const float*)d_in[2];   // (1,1,5,5,5) fp32
    float* out = (float*)d_out;
    float* ws  = (float*)d_ws;
    float* wfac     = ws;         // 9 floats
    float* partials = ws + 16;    // NBLK floats, fully rewritten every launch

    hipLaunchKernelGGL(factorize_window, dim3(1), dim3(64), 0, stream, win, wfac);
    hipLaunchKernelGGL(ssim_main, dim3(NBLK), dim3(256), 0, stream, img1, img2, wfac, partials);
    hipLaunchKernelGGL(finalize_kernel, dim3(1), dim3(256), 0, stream, partials, out);
}